// Round 2
// baseline (1127.859 us; speedup 1.0000x reference)
//
#include <hip/hip_runtime.h>
#include <hip/hip_bf16.h>
#include <cstdint>

// Problem: B=8, S=2048, D=256 fused attention block, fp32 in/out.
// Round 1: fp32 baseline (re-submit after infra failures), ws trimmed to 48MB.
// Pipeline:
//   gemm(x,Wq)->Q  gemm(x,Wk)->K  gemm(x,Wv)->V   (ws: 3 x 16MB)
//   flash-attn(Q,K,V)->ctx                         (ctx lives in d_out)
//   gemm(ctx,Wd)+bd+x->h                           (h overwrites Q buffer)
//   layernorm(h,g,b)->out                          (d_out)

#define RROWS 16384   // B*S
#define DD 256

// ---------------------------------------------------------------------------
// GEMM: out[r][e] = sum_d X[r][d]*W[e][d] + bias[e] (+ res[r][e] if res!=null)
// Tiles: 64x64 output per block, BK=16, 256 threads, 4x4 micro-tile.
// ---------------------------------------------------------------------------
__global__ __launch_bounds__(256) void gemm_bias_kernel(
    const float* __restrict__ X, const float* __restrict__ W,
    const float* __restrict__ bias, const float* __restrict__ res,
    float* __restrict__ out)
{
  __shared__ float Xs[16][68];   // [k][m], pad 68 keeps float4 align + banks spread
  __shared__ float Ws[16][68];   // [k][n]
  const int t    = threadIdx.x;
  const int row0 = blockIdx.x * 64;
  const int col0 = blockIdx.y * 64;
  const int tx   = t >> 4;        // 0..15 row micro-group
  const int ty   = t & 15;        // 0..15 col micro-group (consecutive lanes -> coalesced stores)
  const int lm   = t >> 2;        // 0..63 load row/col
  const int lk   = (t & 3) * 4;   // k offset for load

  float acc[4][4] = {};

  for (int k0 = 0; k0 < DD; k0 += 16) {
    float4 xv = *(const float4*)&X[(size_t)(row0 + lm) * DD + k0 + lk];
    float4 wv = *(const float4*)&W[(size_t)(col0 + lm) * DD + k0 + lk];
    __syncthreads();
    Xs[lk+0][lm] = xv.x; Xs[lk+1][lm] = xv.y; Xs[lk+2][lm] = xv.z; Xs[lk+3][lm] = xv.w;
    Ws[lk+0][lm] = wv.x; Ws[lk+1][lm] = wv.y; Ws[lk+2][lm] = wv.z; Ws[lk+3][lm] = wv.w;
    __syncthreads();
#pragma unroll
    for (int kk = 0; kk < 16; ++kk) {
      float4 a = *(const float4*)&Xs[kk][tx * 4];
      float4 b = *(const float4*)&Ws[kk][ty * 4];
      acc[0][0] += a.x*b.x; acc[0][1] += a.x*b.y; acc[0][2] += a.x*b.z; acc[0][3] += a.x*b.w;
      acc[1][0] += a.y*b.x; acc[1][1] += a.y*b.y; acc[1][2] += a.y*b.z; acc[1][3] += a.y*b.w;
      acc[2][0] += a.z*b.x; acc[2][1] += a.z*b.y; acc[2][2] += a.z*b.z; acc[2][3] += a.z*b.w;
      acc[3][0] += a.w*b.x; acc[3][1] += a.w*b.y; acc[3][2] += a.w*b.z; acc[3][3] += a.w*b.w;
    }
  }

  float4 bv = *(const float4*)&bias[col0 + ty * 4];
#pragma unroll
  for (int i = 0; i < 4; ++i) {
    const int r = row0 + tx * 4 + i;
    float4 o;
    o.x = acc[i][0] + bv.x; o.y = acc[i][1] + bv.y;
    o.z = acc[i][2] + bv.z; o.w = acc[i][3] + bv.w;
    if (res) {
      float4 rv = *(const float4*)&res[(size_t)r * DD + col0 + ty * 4];
      o.x += rv.x; o.y += rv.y; o.z += rv.z; o.w += rv.w;
    }
    *(float4*)&out[(size_t)r * DD + col0 + ty * 4] = o;
  }
}

// ---------------------------------------------------------------------------
// Flash attention (no 1/sqrt(d) scale — faithful to reference).
// Block: 256 threads, 32 q-rows. Key tiles of 64, d-chunked staging (64 cols).
// Thread (rg=t>>4, c=t&15): owns q-rows {2rg,2rg+1}, k-cols {c,c+16,c+32,c+48},
// ctx cols {c*4 + ch*64} per chunk ch. Softmax reduced over the 16-lane
// row group with __shfl_xor (width 16, all within one wave).
// ---------------------------------------------------------------------------
__global__ __launch_bounds__(256) void attn_kernel(
    const float* __restrict__ Q, const float* __restrict__ K,
    const float* __restrict__ V, float* __restrict__ O)
{
  __shared__ float Qs[32][260];   // 33.3 KB, rows 16B-aligned, banks spread
  __shared__ float KVs[64][68];   // 17.4 KB, K or V chunk (64 rows x 64 d-cols)
  __shared__ float Ps[32][68];    // 8.7 KB, probabilities for current tile
  const int t     = threadIdx.x;
  const int batch = blockIdx.y;
  const int q0    = blockIdx.x * 32;
  const size_t base = (size_t)batch * 2048 * DD;
  const int c  = t & 15;
  const int rg = t >> 4;
  const int r0 = rg * 2;
  const int lrow = t >> 2;          // staging row 0..63
  const int lcg  = (t & 3) * 16;    // staging col group

  // stage Q tile once (8 float4 per thread, fully coalesced)
#pragma unroll
  for (int i = 0; i < 8; ++i) {
    int f = i * 256 + t;
    int row = f >> 6, col4 = f & 63;
    *(float4*)&Qs[row][col4 * 4] =
        *(const float4*)&Q[base + (size_t)(q0 + row) * DD + col4 * 4];
  }
  // (first use of Qs is after the syncs inside the kt/ch loop)

  float ctx[2][4][4] = {};
  float mrun[2] = {-1e30f, -1e30f};
  float lrun[2] = {0.f, 0.f};

  for (int kt = 0; kt < 32; ++kt) {
    // ---------------- scores S = Q . K^T (accumulated over 4 d-chunks) ------
    float s[2][4] = {};
    for (int ch = 0; ch < 4; ++ch) {
      __syncthreads();   // everyone done with previous KVs contents
      {
        const float* src = &K[base + (size_t)(kt * 64 + lrow) * DD + ch * 64 + lcg];
        float4 a0 = *(const float4*)&src[0];
        float4 a1 = *(const float4*)&src[4];
        float4 a2 = *(const float4*)&src[8];
        float4 a3 = *(const float4*)&src[12];
        *(float4*)&KVs[lrow][lcg + 0]  = a0;
        *(float4*)&KVs[lrow][lcg + 4]  = a1;
        *(float4*)&KVs[lrow][lcg + 8]  = a2;
        *(float4*)&KVs[lrow][lcg + 12] = a3;
      }
      __syncthreads();
#pragma unroll
      for (int d4 = 0; d4 < 16; ++d4) {
        float4 q0v = *(const float4*)&Qs[r0][ch * 64 + d4 * 4];
        float4 q1v = *(const float4*)&Qs[r0 + 1][ch * 64 + d4 * 4];
#pragma unroll
        for (int j = 0; j < 4; ++j) {
          float4 kv = *(const float4*)&KVs[c + 16 * j][d4 * 4];
          s[0][j] += q0v.x*kv.x + q0v.y*kv.y + q0v.z*kv.z + q0v.w*kv.w;
          s[1][j] += q1v.x*kv.x + q1v.y*kv.y + q1v.z*kv.z + q1v.w*kv.w;
        }
      }
    }
    // ---------------- online softmax --------------------------------------
#pragma unroll
    for (int dr = 0; dr < 2; ++dr) {
      float tmax = fmaxf(fmaxf(s[dr][0], s[dr][1]), fmaxf(s[dr][2], s[dr][3]));
      tmax = fmaxf(tmax, __shfl_xor(tmax, 1, 16));
      tmax = fmaxf(tmax, __shfl_xor(tmax, 2, 16));
      tmax = fmaxf(tmax, __shfl_xor(tmax, 4, 16));
      tmax = fmaxf(tmax, __shfl_xor(tmax, 8, 16));
      float mnew  = fmaxf(mrun[dr], tmax);
      float scale = __expf(mrun[dr] - mnew);
      float psum = 0.f;
#pragma unroll
      for (int j = 0; j < 4; ++j) {
        float p = __expf(s[dr][j] - mnew);
        Ps[r0 + dr][c + 16 * j] = p;   // read back only by this same 16-lane group
        psum += p;
      }
      psum += __shfl_xor(psum, 1, 16);
      psum += __shfl_xor(psum, 2, 16);
      psum += __shfl_xor(psum, 4, 16);
      psum += __shfl_xor(psum, 8, 16);
      lrun[dr] = lrun[dr] * scale + psum;
      mrun[dr] = mnew;
#pragma unroll
      for (int chh = 0; chh < 4; ++chh)
#pragma unroll
        for (int i = 0; i < 4; ++i) ctx[dr][chh][i] *= scale;
    }
    // ---------------- ctx += P . V (4 d-chunks) ----------------------------
    for (int ch = 0; ch < 4; ++ch) {
      __syncthreads();   // S-phase reads of KVs (and Ps writes) complete
      {
        const float* src = &V[base + (size_t)(kt * 64 + lrow) * DD + ch * 64 + lcg];
        float4 a0 = *(const float4*)&src[0];
        float4 a1 = *(const float4*)&src[4];
        float4 a2 = *(const float4*)&src[8];
        float4 a3 = *(const float4*)&src[12];
        *(float4*)&KVs[lrow][lcg + 0]  = a0;
        *(float4*)&KVs[lrow][lcg + 4]  = a1;
        *(float4*)&KVs[lrow][lcg + 8]  = a2;
        *(float4*)&KVs[lrow][lcg + 12] = a3;
      }
      __syncthreads();
#pragma unroll
      for (int k4 = 0; k4 < 16; ++k4) {
        float4 p0 = *(const float4*)&Ps[r0][k4 * 4];
        float4 p1 = *(const float4*)&Ps[r0 + 1][k4 * 4];
        float pa[4] = {p0.x, p0.y, p0.z, p0.w};
        float pb[4] = {p1.x, p1.y, p1.z, p1.w};
#pragma unroll
        for (int kk = 0; kk < 4; ++kk) {
          float4 vv = *(const float4*)&KVs[k4 * 4 + kk][c * 4];
          ctx[0][ch][0] += pa[kk]*vv.x; ctx[0][ch][1] += pa[kk]*vv.y;
          ctx[0][ch][2] += pa[kk]*vv.z; ctx[0][ch][3] += pa[kk]*vv.w;
          ctx[1][ch][0] += pb[kk]*vv.x; ctx[1][ch][1] += pb[kk]*vv.y;
          ctx[1][ch][2] += pb[kk]*vv.z; ctx[1][ch][3] += pb[kk]*vv.w;
        }
      }
    }
  }
  // ---------------- epilogue: ctx / l -> O ---------------------------------
#pragma unroll
  for (int dr = 0; dr < 2; ++dr) {
    float inv = 1.0f / lrun[dr];
#pragma unroll
    for (int ch = 0; ch < 4; ++ch) {
      float4 o;
      o.x = ctx[dr][ch][0] * inv; o.y = ctx[dr][ch][1] * inv;
      o.z = ctx[dr][ch][2] * inv; o.w = ctx[dr][ch][3] * inv;
      *(float4*)&O[base + (size_t)(q0 + r0 + dr) * DD + ch * 64 + c * 4] = o;
    }
  }
}

// ---------------------------------------------------------------------------
// LayerNorm over last dim (256). One wave per row, 4 rows per block.
// Two-pass (mean, then centered var) for accuracy. Safe fully in-place.
// ---------------------------------------------------------------------------
__global__ __launch_bounds__(256) void ln_kernel(
    const float* __restrict__ H, const float* __restrict__ g,
    const float* __restrict__ b, float* __restrict__ out)
{
  const int lane = threadIdx.x & 63;
  const int w    = threadIdx.x >> 6;
  const int r    = blockIdx.x * 4 + w;
  const size_t rowoff = (size_t)r * DD;
  float4 h4 = *(const float4*)&H[rowoff + lane * 4];
  float s = h4.x + h4.y + h4.z + h4.w;
#pragma unroll
  for (int m = 1; m < 64; m <<= 1) s += __shfl_xor(s, m, 64);
  float mu = s * (1.0f / 256.0f);
  float dx = h4.x - mu, dy = h4.y - mu, dz = h4.z - mu, dw = h4.w - mu;
  float v = dx*dx + dy*dy + dz*dz + dw*dw;
#pragma unroll
  for (int m = 1; m < 64; m <<= 1) v += __shfl_xor(v, m, 64);
  float rs = rsqrtf(v * (1.0f / 256.0f) + 1e-5f);
  float4 g4 = *(const float4*)&g[lane * 4];
  float4 b4 = *(const float4*)&b[lane * 4];
  float4 o;
  o.x = dx * rs * g4.x + b4.x;
  o.y = dy * rs * g4.y + b4.y;
  o.z = dz * rs * g4.z + b4.z;
  o.w = dw * rs * g4.w + b4.w;
  *(float4*)&out[rowoff + lane * 4] = o;
}

// ---------------------------------------------------------------------------
extern "C" void kernel_launch(void* const* d_in, const int* in_sizes, int n_in,
                              void* d_out, int out_size, void* d_ws, size_t ws_size,
                              hipStream_t stream) {
  const float* x  = (const float*)d_in[0];
  const float* Wq = (const float*)d_in[1];
  const float* bq = (const float*)d_in[2];
  const float* Wk = (const float*)d_in[3];
  const float* bk = (const float*)d_in[4];
  const float* Wv = (const float*)d_in[5];
  const float* bv = (const float*)d_in[6];
  const float* Wd = (const float*)d_in[7];
  const float* bd = (const float*)d_in[8];
  const float* g  = (const float*)d_in[9];
  const float* b  = (const float*)d_in[10];
  float* out = (float*)d_out;

  const size_t RD = (size_t)RROWS * DD;   // 4 M elements
  float* Qb = (float*)d_ws;               // ws usage: 3*RD*4 = 48 MB
  float* Kb = Qb + RD;
  float* Vb = Kb + RD;
  float* Cb = out;                        // ctx parked in d_out (dead before LN write)

  dim3 gg(RROWS / 64, DD / 64);   // (256, 4)
  dim3 bb(256);

  gemm_bias_kernel<<<gg, bb, 0, stream>>>(x,  Wq, bq, nullptr, Qb);
  gemm_bias_kernel<<<gg, bb, 0, stream>>>(x,  Wk, bk, nullptr, Kb);
  gemm_bias_kernel<<<gg, bb, 0, stream>>>(x,  Wv, bv, nullptr, Vb);

  attn_kernel<<<dim3(2048 / 32, 8), bb, 0, stream>>>(Qb, Kb, Vb, Cb);

  // h = ctx@Wd^T + bd + x, written over the (no longer needed) Q buffer
  gemm_bias_kernel<<<gg, bb, 0, stream>>>(Cb, Wd, bd, x, Qb);

  ln_kernel<<<RROWS / 4, bb, 0, stream>>>(Qb, g, b, out);
}

// Round 6
// 280.086 us; speedup vs baseline: 4.0268x; 4.0268x over previous
//
#include <hip/hip_runtime.h>
#include <hip/hip_bf16.h>
#include <hip/hip_fp16.h>
#include <cstdint>

// B=8, S=2048, D=256 fused attention block, fp32 in/out.
// Round 5 (= round 2 candidate, 3rd resubmit; infra ate all benches):
// attention on fp16 MFMA (16x16x32), fp32 softmax/accum.
//   gemm<F16>(x,Wq)->Qh   gemm<F16>(x,Wk)->Kh   gemm<F16T>(x,Wv)->VtG[b][d][s]
//   attn_mfma(Qh,Kh,VtG)->ctx (d_out, f32)
//   gemm<F32>(ctx,Wd)+bd+x->Hf
//   ln(Hf,g,b)->out
// ws: Qh 8MB | Kh 8MB | VtG 8MB | Hf 16MB = 40MB.

#define RROWS 16384
#define DD 256
#define SEQ 2048
#define NB 8

typedef _Float16 f16x8 __attribute__((ext_vector_type(8)));
typedef _Float16 half4_t __attribute__((ext_vector_type(4)));
typedef float f32x4 __attribute__((ext_vector_type(4)));

// ---------------------------------------------------------------------------
// GEMM: out[r][e] = sum_d X[r][d]*W[e][d] + bias[e] (+res). 64x64 tile, BK=16.
// MODE 0: f32 out (+optional res)   MODE 1: f16 out   MODE 2: f16 transposed
// out[b][e][s] (for V^T).
// ---------------------------------------------------------------------------
template <int MODE>
__global__ __launch_bounds__(256) void gemm_bias_kernel(
    const float* __restrict__ X, const float* __restrict__ W,
    const float* __restrict__ bias, const float* __restrict__ res,
    void* __restrict__ outv)
{
  __shared__ float Xs[16][68];
  __shared__ float Ws[16][68];
  const int t    = threadIdx.x;
  const int row0 = blockIdx.x * 64;
  const int col0 = blockIdx.y * 64;
  const int tx   = t >> 4;
  const int ty   = t & 15;
  const int lm   = t >> 2;
  const int lk   = (t & 3) * 4;

  float acc[4][4] = {};

  for (int k0 = 0; k0 < DD; k0 += 16) {
    float4 xv = *(const float4*)&X[(size_t)(row0 + lm) * DD + k0 + lk];
    float4 wv = *(const float4*)&W[(size_t)(col0 + lm) * DD + k0 + lk];
    __syncthreads();
    Xs[lk+0][lm] = xv.x; Xs[lk+1][lm] = xv.y; Xs[lk+2][lm] = xv.z; Xs[lk+3][lm] = xv.w;
    Ws[lk+0][lm] = wv.x; Ws[lk+1][lm] = wv.y; Ws[lk+2][lm] = wv.z; Ws[lk+3][lm] = wv.w;
    __syncthreads();
#pragma unroll
    for (int kk = 0; kk < 16; ++kk) {
      float4 a = *(const float4*)&Xs[kk][tx * 4];
      float4 b = *(const float4*)&Ws[kk][ty * 4];
      acc[0][0] += a.x*b.x; acc[0][1] += a.x*b.y; acc[0][2] += a.x*b.z; acc[0][3] += a.x*b.w;
      acc[1][0] += a.y*b.x; acc[1][1] += a.y*b.y; acc[1][2] += a.y*b.z; acc[1][3] += a.y*b.w;
      acc[2][0] += a.z*b.x; acc[2][1] += a.z*b.y; acc[2][2] += a.z*b.z; acc[2][3] += a.z*b.w;
      acc[3][0] += a.w*b.x; acc[3][1] += a.w*b.y; acc[3][2] += a.w*b.z; acc[3][3] += a.w*b.w;
    }
  }

  float4 bv = *(const float4*)&bias[col0 + ty * 4];
  float bvv[4] = {bv.x, bv.y, bv.z, bv.w};

  if constexpr (MODE == 0) {
    float* out = (float*)outv;
#pragma unroll
    for (int i = 0; i < 4; ++i) {
      const int r = row0 + tx * 4 + i;
      float4 o;
      o.x = acc[i][0] + bvv[0]; o.y = acc[i][1] + bvv[1];
      o.z = acc[i][2] + bvv[2]; o.w = acc[i][3] + bvv[3];
      if (res) {
        float4 rv = *(const float4*)&res[(size_t)r * DD + col0 + ty * 4];
        o.x += rv.x; o.y += rv.y; o.z += rv.z; o.w += rv.w;
      }
      *(float4*)&out[(size_t)r * DD + col0 + ty * 4] = o;
    }
  } else if constexpr (MODE == 1) {
    _Float16* out = (_Float16*)outv;
#pragma unroll
    for (int i = 0; i < 4; ++i) {
      const int r = row0 + tx * 4 + i;
      half4_t h = { (_Float16)(acc[i][0] + bvv[0]), (_Float16)(acc[i][1] + bvv[1]),
                    (_Float16)(acc[i][2] + bvv[2]), (_Float16)(acc[i][3] + bvv[3]) };
      *(half4_t*)&out[(size_t)r * DD + col0 + ty * 4] = h;
    }
  } else {  // MODE 2: transposed fp16, out[b][e][s], b = row block's batch
    _Float16* out = (_Float16*)outv;
    const int bIdx = row0 >> 11;            // row0 multiple of 64, 2048%64==0
    const int s0   = (row0 & (SEQ - 1)) + tx * 4;
#pragma unroll
    for (int j = 0; j < 4; ++j) {
      const int e = col0 + ty * 4 + j;
      half4_t h = { (_Float16)(acc[0][j] + bvv[j]), (_Float16)(acc[1][j] + bvv[j]),
                    (_Float16)(acc[2][j] + bvv[j]), (_Float16)(acc[3][j] + bvv[j]) };
      *(half4_t*)&out[((size_t)bIdx * DD + e) * SEQ + s0] = h;
    }
  }
}

// ---------------------------------------------------------------------------
// MFMA flash attention. Block = 128 thr (2 waves), QBLK=32 (16 rows/wave),
// KVBLK=32, D=256. fp16 inputs, fp32 softmax + accumulators.
// Frag convention: A row = lane&15, B col = lane&15, k = (lane>>4)*8 + i
// (same linear k order for A and B -> permutation-safe).
// C/D (HW-verified): col = lane&15, row = (lane>>4)*4 + reg.
// LDS pads: Ks pitch 264 halfs (528B: bank walk 4r%32, 8 words/bank/wave-read
// = inherent minimum), Vt/Ps pitch 40 halfs (80B: walk 20r%32, same property).
// ---------------------------------------------------------------------------
__global__ __launch_bounds__(128) void attn_mfma_kernel(
    const _Float16* __restrict__ Q, const _Float16* __restrict__ K,
    const _Float16* __restrict__ VT, float* __restrict__ O)
{
  __shared__ _Float16 Ks[32][264];      // 16.9 KB
  __shared__ _Float16 Vt[256][40];      // 20.5 KB  (V^T tile: [d][k])
  __shared__ _Float16 Ps[2][16][40];    //  2.5 KB  (per-wave P tile)

  const int t    = threadIdx.x;
  const int lane = t & 63;
  const int w    = t >> 6;              // wave 0..1
  const int b    = blockIdx.y;
  const int q0   = blockIdx.x * 32;
  const _Float16* Qb = Q  + (size_t)b * SEQ * DD;
  const _Float16* Kb = K  + (size_t)b * SEQ * DD;
  const _Float16* Vb = VT + (size_t)b * DD * SEQ;   // [256][2048]
  const int lr = lane & 15;
  const int lg = lane >> 4;

  // Q fragments for this wave's 16 rows: 8 k-steps x f16x8 (32 VGPR)
  f16x8 qf[8];
  {
    const _Float16* qrow = Qb + (size_t)(q0 + w * 16 + lr) * DD;
#pragma unroll
    for (int ks = 0; ks < 8; ++ks)
      qf[ks] = *(const f16x8*)(qrow + ks * 32 + lg * 8);
  }

  f32x4 cacc[16];
#pragma unroll
  for (int i = 0; i < 16; ++i) cacc[i] = (f32x4){0.f, 0.f, 0.f, 0.f};
  float mrun[4] = {-1e30f, -1e30f, -1e30f, -1e30f};
  float lrun[4] = {0.f, 0.f, 0.f, 0.f};

  f16x8 kreg[8], vreg[8];   // prefetch registers (64 VGPR)

  auto LOAD = [&](int kt) {
    const _Float16* ksrc = Kb + (size_t)kt * 32 * DD;
#pragma unroll
    for (int i = 0; i < 8; ++i) {
      int ch = i * 128 + t;                      // K tile: 32 rows x 256 halfs
      kreg[i] = *(const f16x8*)(ksrc + (ch >> 5) * DD + (ch & 31) * 8);
    }
#pragma unroll
    for (int i = 0; i < 8; ++i) {
      int ch = i * 128 + t;                      // V^T tile: 256 rows x 32 halfs
      vreg[i] = *(const f16x8*)(Vb + (size_t)(ch >> 2) * SEQ + kt * 32 + (ch & 3) * 8);
    }
  };
  auto STORE = [&]() {
#pragma unroll
    for (int i = 0; i < 8; ++i) {
      int ch = i * 128 + t;
      *(f16x8*)(&Ks[ch >> 5][(ch & 31) * 8]) = kreg[i];
    }
#pragma unroll
    for (int i = 0; i < 8; ++i) {
      int ch = i * 128 + t;
      *(f16x8*)(&Vt[ch >> 2][(ch & 3) * 8]) = vreg[i];
    }
  };

  LOAD(0); STORE(); __syncthreads();

  for (int kt = 0; kt < SEQ / 32; ++kt) {
    if (kt + 1 < SEQ / 32) LOAD(kt + 1);   // issue early; hidden under compute

    // ---- S = Q.K^T : 2 col-tiles x 8 k-steps --------------------------------
    f32x4 sc[2] = {(f32x4){0.f,0.f,0.f,0.f}, (f32x4){0.f,0.f,0.f,0.f}};
#pragma unroll
    for (int ct = 0; ct < 2; ++ct)
#pragma unroll
      for (int ks = 0; ks < 8; ++ks) {
        f16x8 kf = *(const f16x8*)(&Ks[ct * 16 + lr][ks * 32 + lg * 8]);
        sc[ct] = __builtin_amdgcn_mfma_f32_16x16x32_f16(qf[ks], kf, sc[ct], 0, 0, 0);
      }

    // ---- online softmax (lane owns 4 q-rows, 2 k-cols) ----------------------
    float scl[4];
#pragma unroll
    for (int j = 0; j < 4; ++j) {
      float tm = fmaxf(sc[0][j], sc[1][j]);
      tm = fmaxf(tm, __shfl_xor(tm, 1, 16));
      tm = fmaxf(tm, __shfl_xor(tm, 2, 16));
      tm = fmaxf(tm, __shfl_xor(tm, 4, 16));
      tm = fmaxf(tm, __shfl_xor(tm, 8, 16));
      float mnew = fmaxf(mrun[j], tm);
      scl[j] = __expf(mrun[j] - mnew);
      float p0 = __expf(sc[0][j] - mnew);
      float p1 = __expf(sc[1][j] - mnew);
      sc[0][j] = p0; sc[1][j] = p1;
      float ps = p0 + p1;
      ps += __shfl_xor(ps, 1, 16);
      ps += __shfl_xor(ps, 2, 16);
      ps += __shfl_xor(ps, 4, 16);
      ps += __shfl_xor(ps, 8, 16);
      lrun[j] = lrun[j] * scl[j] + ps;
      mrun[j] = mnew;
    }

    // ---- P -> LDS (fp16), per-wave region, no barrier needed ---------------
#pragma unroll
    for (int ct = 0; ct < 2; ++ct)
#pragma unroll
      for (int j = 0; j < 4; ++j)
        Ps[w][lg * 4 + j][ct * 16 + lr] = (_Float16)sc[ct][j];

    // ---- rescale ctx --------------------------------------------------------
#pragma unroll
    for (int dt = 0; dt < 16; ++dt)
#pragma unroll
      for (int j = 0; j < 4; ++j) cacc[dt][j] *= scl[j];

    // ---- ctx += P.V : 16 d-tiles x 1 k-step ---------------------------------
    f16x8 pa = *(const f16x8*)(&Ps[w][lr][lg * 8]);
#pragma unroll
    for (int dt = 0; dt < 16; ++dt) {
      f16x8 vf = *(const f16x8*)(&Vt[dt * 16 + lr][lg * 8]);
      cacc[dt] = __builtin_amdgcn_mfma_f32_16x16x32_f16(pa, vf, cacc[dt], 0, 0, 0);
    }

    __syncthreads();                         // all waves done reading Ks/Vt
    if (kt + 1 < SEQ / 32) STORE();          // vmcnt waits land here, hidden
    __syncthreads();                         // staged tile visible
  }

  // ---- epilogue: ctx / l -> O (fp32) ---------------------------------------
  float* Ob = O + (size_t)b * SEQ * DD;
#pragma unroll
  for (int j = 0; j < 4; ++j) {
    float inv = 1.0f / lrun[j];
    int r = q0 + w * 16 + lg * 4 + j;
#pragma unroll
    for (int dt = 0; dt < 16; ++dt)
      Ob[(size_t)r * DD + dt * 16 + lr] = cacc[dt][j] * inv;
  }
}

// ---------------------------------------------------------------------------
// LayerNorm over last dim (256). One wave per row, 4 rows per block.
// ---------------------------------------------------------------------------
__global__ __launch_bounds__(256) void ln_kernel(
    const float* __restrict__ H, const float* __restrict__ g,
    const float* __restrict__ b, float* __restrict__ out)
{
  const int lane = threadIdx.x & 63;
  const int w    = threadIdx.x >> 6;
  const int r    = blockIdx.x * 4 + w;
  const size_t rowoff = (size_t)r * DD;
  float4 h4 = *(const float4*)&H[rowoff + lane * 4];
  float s = h4.x + h4.y + h4.z + h4.w;
#pragma unroll
  for (int m = 1; m < 64; m <<= 1) s += __shfl_xor(s, m, 64);
  float mu = s * (1.0f / 256.0f);
  float dx = h4.x - mu, dy = h4.y - mu, dz = h4.z - mu, dw = h4.w - mu;
  float v = dx*dx + dy*dy + dz*dz + dw*dw;
#pragma unroll
  for (int m = 1; m < 64; m <<= 1) v += __shfl_xor(v, m, 64);
  float rs = rsqrtf(v * (1.0f / 256.0f) + 1e-5f);
  float4 g4 = *(const float4*)&g[lane * 4];
  float4 b4 = *(const float4*)&b[lane * 4];
  float4 o;
  o.x = dx * rs * g4.x + b4.x;
  o.y = dy * rs * g4.y + b4.y;
  o.z = dz * rs * g4.z + b4.z;
  o.w = dw * rs * g4.w + b4.w;
  *(float4*)&out[rowoff + lane * 4] = o;
}

// ---------------------------------------------------------------------------
extern "C" void kernel_launch(void* const* d_in, const int* in_sizes, int n_in,
                              void* d_out, int out_size, void* d_ws, size_t ws_size,
                              hipStream_t stream) {
  const float* x  = (const float*)d_in[0];
  const float* Wq = (const float*)d_in[1];
  const float* bq = (const float*)d_in[2];
  const float* Wk = (const float*)d_in[3];
  const float* bk = (const float*)d_in[4];
  const float* Wv = (const float*)d_in[5];
  const float* bv = (const float*)d_in[6];
  const float* Wd = (const float*)d_in[7];
  const float* bd = (const float*)d_in[8];
  const float* g  = (const float*)d_in[9];
  const float* b  = (const float*)d_in[10];
  float* out = (float*)d_out;

  const size_t RD = (size_t)RROWS * DD;       // 4 M elements
  _Float16* Qh  = (_Float16*)d_ws;            //  8 MB
  _Float16* Kh  = Qh + RD;                    //  8 MB
  _Float16* VtG = Kh + RD;                    //  8 MB, layout [b][d][s]
  float*    Hf  = (float*)(VtG + RD);         // 16 MB
  float*    ctx = out;                        // ctx parked in d_out (f32)

  dim3 gg(RROWS / 64, DD / 64);   // (256, 4)
  dim3 bb(256);

  gemm_bias_kernel<1><<<gg, bb, 0, stream>>>(x, Wq, bq, nullptr, Qh);
  gemm_bias_kernel<1><<<gg, bb, 0, stream>>>(x, Wk, bk, nullptr, Kh);
  gemm_bias_kernel<2><<<gg, bb, 0, stream>>>(x, Wv, bv, nullptr, VtG);

  attn_mfma_kernel<<<dim3(SEQ / 32, NB), dim3(128), 0, stream>>>(Qh, Kh, VtG, ctx);

  gemm_bias_kernel<0><<<gg, bb, 0, stream>>>(ctx, Wd, bd, x, Hf);

  ln_kernel<<<RROWS / 4, bb, 0, stream>>>(Hf, g, b, out);
}

// Round 8
// 199.889 us; speedup vs baseline: 5.6424x; 1.4012x over previous
//
#include <hip/hip_runtime.h>
#include <hip/hip_bf16.h>
#include <hip/hip_fp16.h>
#include <cstdint>

// B=8, S=2048, D=256 fused attention block, fp32 in/out.
// Round 7 (= round 6 candidate resubmit; infra ate the bench):
// (a) split-K flash attention (NSPLIT=2) to fix grid-limited 11% occupancy;
// (b) all GEMMs on fp16 MFMA (fragment layout HW-validated by round-5 attn);
// (c) V^T store via LDS transpose (coalesced).
// Pipeline:
//   cast x->xh f16, {Wq,Wk,Wv,Wd}->Wh f16
//   gemm16<1>(xh,Whq)->Qh    gemm16<1>(xh,Whk)->Kh    gemm16<2>(xh,Whv)->VtG
//   attn_partial (split 0/1) -> Op(f16, unnormalized), Mp, Lp
//   combine -> ctxh (f16, overlays Qh)
//   gemm16<0>(ctxh,Whd)+bd+x -> Hf (f32, overlays Op)
//   ln(Hf) -> out
// ws: xh 8 | Qh 8 | Kh 8 | VtG 8 | Op 16 (=Hf 16) | Mp/Lp 0.25 | Wh 0.5 = 48.75MB

#define RROWS 16384
#define DD 256
#define SEQ 2048
#define NB 8
#define NSPLIT 2
#define NT_SPLIT 32           // kv tiles (of 32) per split: 64/NSPLIT

typedef _Float16 f16x8 __attribute__((ext_vector_type(8)));
typedef _Float16 f16x4 __attribute__((ext_vector_type(4)));
typedef float f32x4 __attribute__((ext_vector_type(4)));

// ---------------------------------------------------------------------------
// casts
// ---------------------------------------------------------------------------
__global__ __launch_bounds__(256) void cast_x_kernel(
    const float* __restrict__ src, _Float16* __restrict__ dst)
{
  const size_t i = ((size_t)blockIdx.x * 256 + threadIdx.x) * 8;
  float4 a = *(const float4*)&src[i];
  float4 b = *(const float4*)&src[i + 4];
  f16x8 h = { (_Float16)a.x, (_Float16)a.y, (_Float16)a.z, (_Float16)a.w,
              (_Float16)b.x, (_Float16)b.y, (_Float16)b.z, (_Float16)b.w };
  *(f16x8*)&dst[i] = h;
}

__global__ __launch_bounds__(256) void cast_w_kernel(
    const float* __restrict__ w0, const float* __restrict__ w1,
    const float* __restrict__ w2, const float* __restrict__ w3,
    _Float16* __restrict__ dst)
{
  const float* srcs[4] = {w0, w1, w2, w3};
  const float* src = srcs[blockIdx.y];
  _Float16* d = dst + (size_t)blockIdx.y * 65536;
  const size_t i = ((size_t)blockIdx.x * 256 + threadIdx.x) * 8;
  float4 a = *(const float4*)&src[i];
  float4 b = *(const float4*)&src[i + 4];
  f16x8 h = { (_Float16)a.x, (_Float16)a.y, (_Float16)a.z, (_Float16)a.w,
              (_Float16)b.x, (_Float16)b.y, (_Float16)b.z, (_Float16)b.w };
  *(f16x8*)&d[i] = h;
}

// ---------------------------------------------------------------------------
// fp16 MFMA GEMM: out[r][e] = sum_d X[r][d] * W[e][d] + bias[e] (+res f32).
// Tile: 64 rows x 128 cols, K=256 (no K loop). 256 thr = 4 waves, wave w owns
// rows rows0+w*16.. Per wave: 8 ct x 8 ks = 64 MFMA, 8 independent chains.
// W-tile staged in LDS (pitch 264 halfs — attn-proven conflict-free pattern).
// MODE 0: f32 out + res.  MODE 1: f16 out row-major.  MODE 2: f16 out
// transposed [b][e][s] via LDS transpose stage (coalesced global writes).
// ---------------------------------------------------------------------------
template <int MODE>
__global__ __launch_bounds__(256) void gemm16_kernel(
    const _Float16* __restrict__ X, const _Float16* __restrict__ W,
    const float* __restrict__ bias, const float* __restrict__ res,
    void* __restrict__ outv)
{
  __shared__ _Float16 smem[128 * 264];   // 67.6 KB: W-tile [128 e][264]
  const int t     = threadIdx.x;
  const int lane  = t & 63;
  const int w     = t >> 6;
  const int rows0 = blockIdx.x * 64;
  const int col0  = blockIdx.y * 128;
  const int lr = lane & 15;
  const int lg = lane >> 4;

  // stage W tile: 128 rows x 256 halfs
#pragma unroll
  for (int i = 0; i < 16; ++i) {
    int ch = i * 256 + t;
    int er = ch >> 5, kc = (ch & 31) * 8;
    *(f16x8*)&smem[er * 264 + kc] = *(const f16x8*)&W[(size_t)(col0 + er) * DD + kc];
  }

  // A fragments: 16 rows x K=256 per wave
  f16x8 qf[8];
  {
    const _Float16* xrow = X + (size_t)(rows0 + w * 16 + lr) * DD;
#pragma unroll
    for (int ks = 0; ks < 8; ++ks)
      qf[ks] = *(const f16x8*)(xrow + ks * 32 + lg * 8);
  }
  __syncthreads();

  f32x4 acc[8];
#pragma unroll
  for (int i = 0; i < 8; ++i) acc[i] = (f32x4){0.f, 0.f, 0.f, 0.f};

#pragma unroll
  for (int ct = 0; ct < 8; ++ct)
#pragma unroll
    for (int ks = 0; ks < 8; ++ks) {
      f16x8 wf = *(const f16x8*)&smem[(ct * 16 + lr) * 264 + ks * 32 + lg * 8];
      acc[ct] = __builtin_amdgcn_mfma_f32_16x16x32_f16(qf[ks], wf, acc[ct], 0, 0, 0);
    }

  // bias per (ct): channel e = col0 + ct*16 + lr
  float bf[8];
#pragma unroll
  for (int ct = 0; ct < 8; ++ct) bf[ct] = bias[col0 + ct * 16 + lr];

  if constexpr (MODE == 0) {
    float* out = (float*)outv;
#pragma unroll
    for (int ct = 0; ct < 8; ++ct)
#pragma unroll
      for (int j = 0; j < 4; ++j) {
        int r = rows0 + w * 16 + lg * 4 + j;
        int c = col0 + ct * 16 + lr;
        out[(size_t)r * DD + c] = acc[ct][j] + bf[ct] + res[(size_t)r * DD + c];
      }
  } else if constexpr (MODE == 1) {
    _Float16* out = (_Float16*)outv;
#pragma unroll
    for (int ct = 0; ct < 8; ++ct)
#pragma unroll
      for (int j = 0; j < 4; ++j) {
        int r = rows0 + w * 16 + lg * 4 + j;
        out[(size_t)r * DD + col0 + ct * 16 + lr] = (_Float16)(acc[ct][j] + bf[ct]);
      }
  } else {  // MODE 2: out[b][e][s] via LDS transpose
    __syncthreads();   // all waves done reading W-tile from smem
    _Float16* T = smem;   // reuse: [128 e][72 s-pitch]
#pragma unroll
    for (int ct = 0; ct < 8; ++ct)
#pragma unroll
      for (int j = 0; j < 4; ++j)
        T[(ct * 16 + lr) * 72 + (w * 16 + lg * 4 + j)] = (_Float16)(acc[ct][j] + bf[ct]);
    __syncthreads();
    _Float16* out = (_Float16*)outv;
    const int bIdx = rows0 >> 11;
    const int s0   = rows0 & (SEQ - 1);
#pragma unroll
    for (int p = 0; p < 4; ++p) {
      int ch = p * 256 + t;
      int e = ch >> 3, sc = (ch & 7) * 8;
      *(f16x8*)&out[((size_t)bIdx * DD + col0 + e) * SEQ + s0 + sc] =
          *(const f16x8*)&T[e * 72 + sc];
    }
  }
}

// ---------------------------------------------------------------------------
// Split-K MFMA flash attention. Block = 128 thr (2 waves), QBLK=32, KVBLK=32.
// blockIdx: (q-tile, split, batch). Each split covers 1024 kv rows; outputs
// UNNORMALIZED partial ctx (f16) + running max/denominator (f32) per row.
// Inner structure identical to the round-5 validated kernel.
// ---------------------------------------------------------------------------
__global__ __launch_bounds__(128) void attn_partial_kernel(
    const _Float16* __restrict__ Q, const _Float16* __restrict__ K,
    const _Float16* __restrict__ VT, _Float16* __restrict__ Op,
    float* __restrict__ Mp, float* __restrict__ Lp)
{
  __shared__ _Float16 Ks[32][264];
  __shared__ _Float16 Vt[256][40];
  __shared__ _Float16 Ps[2][16][40];

  const int t     = threadIdx.x;
  const int lane  = t & 63;
  const int w     = t >> 6;
  const int split = blockIdx.y;
  const int b     = blockIdx.z;
  const int q0    = blockIdx.x * 32;
  const int kt0   = split * NT_SPLIT;
  const _Float16* Qb = Q  + (size_t)b * SEQ * DD;
  const _Float16* Kb = K  + (size_t)b * SEQ * DD;
  const _Float16* Vb = VT + (size_t)b * DD * SEQ;
  const int lr = lane & 15;
  const int lg = lane >> 4;

  f16x8 qf[8];
  {
    const _Float16* qrow = Qb + (size_t)(q0 + w * 16 + lr) * DD;
#pragma unroll
    for (int ks = 0; ks < 8; ++ks)
      qf[ks] = *(const f16x8*)(qrow + ks * 32 + lg * 8);
  }

  f32x4 cacc[16];
#pragma unroll
  for (int i = 0; i < 16; ++i) cacc[i] = (f32x4){0.f, 0.f, 0.f, 0.f};
  float mrun[4] = {-1e30f, -1e30f, -1e30f, -1e30f};
  float lrun[4] = {0.f, 0.f, 0.f, 0.f};

  f16x8 kreg[8], vreg[8];

  auto LOAD = [&](int kt) {
    const _Float16* ksrc = Kb + (size_t)kt * 32 * DD;
#pragma unroll
    for (int i = 0; i < 8; ++i) {
      int ch = i * 128 + t;
      kreg[i] = *(const f16x8*)(ksrc + (ch >> 5) * DD + (ch & 31) * 8);
    }
#pragma unroll
    for (int i = 0; i < 8; ++i) {
      int ch = i * 128 + t;
      vreg[i] = *(const f16x8*)(Vb + (size_t)(ch >> 2) * SEQ + kt * 32 + (ch & 3) * 8);
    }
  };
  auto STORE = [&]() {
#pragma unroll
    for (int i = 0; i < 8; ++i) {
      int ch = i * 128 + t;
      *(f16x8*)(&Ks[ch >> 5][(ch & 31) * 8]) = kreg[i];
    }
#pragma unroll
    for (int i = 0; i < 8; ++i) {
      int ch = i * 128 + t;
      *(f16x8*)(&Vt[ch >> 2][(ch & 3) * 8]) = vreg[i];
    }
  };

  LOAD(kt0); STORE(); __syncthreads();

  for (int kt = kt0; kt < kt0 + NT_SPLIT; ++kt) {
    if (kt + 1 < kt0 + NT_SPLIT) LOAD(kt + 1);

    f32x4 sc[2] = {(f32x4){0.f,0.f,0.f,0.f}, (f32x4){0.f,0.f,0.f,0.f}};
#pragma unroll
    for (int ct = 0; ct < 2; ++ct)
#pragma unroll
      for (int ks = 0; ks < 8; ++ks) {
        f16x8 kf = *(const f16x8*)(&Ks[ct * 16 + lr][ks * 32 + lg * 8]);
        sc[ct] = __builtin_amdgcn_mfma_f32_16x16x32_f16(qf[ks], kf, sc[ct], 0, 0, 0);
      }

    float scl[4];
#pragma unroll
    for (int j = 0; j < 4; ++j) {
      float tm = fmaxf(sc[0][j], sc[1][j]);
      tm = fmaxf(tm, __shfl_xor(tm, 1, 16));
      tm = fmaxf(tm, __shfl_xor(tm, 2, 16));
      tm = fmaxf(tm, __shfl_xor(tm, 4, 16));
      tm = fmaxf(tm, __shfl_xor(tm, 8, 16));
      float mnew = fmaxf(mrun[j], tm);
      scl[j] = __expf(mrun[j] - mnew);
      float p0 = __expf(sc[0][j] - mnew);
      float p1 = __expf(sc[1][j] - mnew);
      sc[0][j] = p0; sc[1][j] = p1;
      float ps = p0 + p1;
      ps += __shfl_xor(ps, 1, 16);
      ps += __shfl_xor(ps, 2, 16);
      ps += __shfl_xor(ps, 4, 16);
      ps += __shfl_xor(ps, 8, 16);
      lrun[j] = lrun[j] * scl[j] + ps;
      mrun[j] = mnew;
    }

#pragma unroll
    for (int ct = 0; ct < 2; ++ct)
#pragma unroll
      for (int j = 0; j < 4; ++j)
        Ps[w][lg * 4 + j][ct * 16 + lr] = (_Float16)sc[ct][j];

#pragma unroll
    for (int dt = 0; dt < 16; ++dt)
#pragma unroll
      for (int j = 0; j < 4; ++j) cacc[dt][j] *= scl[j];

    f16x8 pa = *(const f16x8*)(&Ps[w][lr][lg * 8]);
#pragma unroll
    for (int dt = 0; dt < 16; ++dt) {
      f16x8 vf = *(const f16x8*)(&Vt[dt * 16 + lr][lg * 8]);
      cacc[dt] = __builtin_amdgcn_mfma_f32_16x16x32_f16(pa, vf, cacc[dt], 0, 0, 0);
    }

    __syncthreads();
    if (kt + 1 < kt0 + NT_SPLIT) STORE();
    __syncthreads();
  }

  // epilogue: UNNORMALIZED partial ctx (f16) + m/l (f32)
  const size_t Rbase = (size_t)b * SEQ + q0 + w * 16;
#pragma unroll
  for (int j = 0; j < 4; ++j) {
    size_t R = Rbase + lg * 4 + j;
    if (lr == 0) {
      Mp[(size_t)split * RROWS + R] = mrun[j];
      Lp[(size_t)split * RROWS + R] = lrun[j];
    }
#pragma unroll
    for (int dt = 0; dt < 16; ++dt)
      Op[((size_t)split * RROWS + R) * DD + dt * 16 + lr] = (_Float16)cacc[dt][j];
  }
}

// ---------------------------------------------------------------------------
// Combine the NSPLIT partials: ctx = (sum_i e^{mi-m*} Oi) / (sum_i e^{mi-m*} li)
// One wave per row; lane owns 4 columns. f16 output (feeds the out-proj GEMM).
// ---------------------------------------------------------------------------
__global__ __launch_bounds__(256) void attn_combine_kernel(
    const _Float16* __restrict__ Op, const float* __restrict__ Mp,
    const float* __restrict__ Lp, _Float16* __restrict__ ctx)
{
  const int lane = threadIdx.x & 63;
  const int w    = threadIdx.x >> 6;
  const size_t R = (size_t)blockIdx.x * 4 + w;
  float m0 = Mp[R], m1 = Mp[RROWS + R];
  float l0 = Lp[R], l1 = Lp[RROWS + R];
  float ms = fmaxf(m0, m1);
  float w0 = __expf(m0 - ms), w1 = __expf(m1 - ms);
  float linv = 1.0f / (w0 * l0 + w1 * l1);
  w0 *= linv; w1 *= linv;
  f16x4 o0 = *(const f16x4*)&Op[R * DD + lane * 4];
  f16x4 o1 = *(const f16x4*)&Op[((size_t)RROWS + R) * DD + lane * 4];
  f16x4 o;
#pragma unroll
  for (int i = 0; i < 4; ++i)
    o[i] = (_Float16)(w0 * (float)o0[i] + w1 * (float)o1[i]);
  *(f16x4*)&ctx[R * DD + lane * 4] = o;
}

// ---------------------------------------------------------------------------
// LayerNorm over last dim (256). One wave per row, 4 rows per block.
// ---------------------------------------------------------------------------
__global__ __launch_bounds__(256) void ln_kernel(
    const float* __restrict__ H, const float* __restrict__ g,
    const float* __restrict__ b, float* __restrict__ out)
{
  const int lane = threadIdx.x & 63;
  const int w    = threadIdx.x >> 6;
  const int r    = blockIdx.x * 4 + w;
  const size_t rowoff = (size_t)r * DD;
  float4 h4 = *(const float4*)&H[rowoff + lane * 4];
  float s = h4.x + h4.y + h4.z + h4.w;
#pragma unroll
  for (int m = 1; m < 64; m <<= 1) s += __shfl_xor(s, m, 64);
  float mu = s * (1.0f / 256.0f);
  float dx = h4.x - mu, dy = h4.y - mu, dz = h4.z - mu, dw = h4.w - mu;
  float v = dx*dx + dy*dy + dz*dz + dw*dw;
#pragma unroll
  for (int m = 1; m < 64; m <<= 1) v += __shfl_xor(v, m, 64);
  float rs = rsqrtf(v * (1.0f / 256.0f) + 1e-5f);
  float4 g4 = *(const float4*)&g[lane * 4];
  float4 b4 = *(const float4*)&b[lane * 4];
  float4 o;
  o.x = dx * rs * g4.x + b4.x;
  o.y = dy * rs * g4.y + b4.y;
  o.z = dz * rs * g4.z + b4.z;
  o.w = dw * rs * g4.w + b4.w;
  *(float4*)&out[rowoff + lane * 4] = o;
}

// ---------------------------------------------------------------------------
extern "C" void kernel_launch(void* const* d_in, const int* in_sizes, int n_in,
                              void* d_out, int out_size, void* d_ws, size_t ws_size,
                              hipStream_t stream) {
  const float* x  = (const float*)d_in[0];
  const float* Wq = (const float*)d_in[1];
  const float* bq = (const float*)d_in[2];
  const float* Wk = (const float*)d_in[3];
  const float* bk = (const float*)d_in[4];
  const float* Wv = (const float*)d_in[5];
  const float* bv = (const float*)d_in[6];
  const float* Wd = (const float*)d_in[7];
  const float* bd = (const float*)d_in[8];
  const float* g  = (const float*)d_in[9];
  const float* b  = (const float*)d_in[10];
  float* out = (float*)d_out;

  const size_t RD = (size_t)RROWS * DD;         // 4 M elements
  _Float16* ws16 = (_Float16*)d_ws;
  _Float16* xh   = ws16;                        //  8 MB  [cast -> proj gemms]
  _Float16* Qh   = ws16 + RD;                   //  8 MB  [-> attn]; then ctx
  _Float16* Kh   = ws16 + 2 * RD;               //  8 MB
  _Float16* VtG  = ws16 + 3 * RD;               //  8 MB, [b][d][s]
  _Float16* Op   = ws16 + 4 * RD;               // 16 MB  [attn -> combine]
  float*    Hf   = (float*)(ws16 + 4 * RD);     // 16 MB  overlays Op (dead)
  float*    Mp   = (float*)(ws16 + 6 * RD);     // 128 KB
  float*    Lp   = Mp + (size_t)NSPLIT * RROWS; // 128 KB
  _Float16* Wh   = (_Float16*)(Lp + (size_t)NSPLIT * RROWS);  // 512 KB
  _Float16* ctxh = Qh;                          // overlays Qh (dead after attn)

  cast_x_kernel<<<2048, 256, 0, stream>>>(x, xh);
  cast_w_kernel<<<dim3(32, 4), 256, 0, stream>>>(Wq, Wk, Wv, Wd, Wh);

  dim3 gg(RROWS / 64, DD / 128);   // (256, 2)
  gemm16_kernel<1><<<gg, 256, 0, stream>>>(xh, Wh,             bq, nullptr, Qh);
  gemm16_kernel<1><<<gg, 256, 0, stream>>>(xh, Wh + 65536,     bk, nullptr, Kh);
  gemm16_kernel<2><<<gg, 256, 0, stream>>>(xh, Wh + 2 * 65536, bv, nullptr, VtG);

  attn_partial_kernel<<<dim3(SEQ / 32, NSPLIT, NB), 128, 0, stream>>>(
      Qh, Kh, VtG, Op, Mp, Lp);
  attn_combine_kernel<<<RROWS / 4, 256, 0, stream>>>(Op, Mp, Lp, ctxh);

  gemm16_kernel<0><<<gg, 256, 0, stream>>>(ctxh, Wh + 3 * 65536, bd, x, Hf);

  ln_kernel<<<RROWS / 4, 256, 0, stream>>>(Hf, g, b, out);
}